// Round 5
// baseline (1484.771 us; speedup 1.0000x reference)
//
#include <hip/hip_runtime.h>
#include <hip/hip_cooperative_groups.h>

#define HH 2048
#define WW 2048
#define NPX (HH*WW)
#define INFV 1e30f
#define TS 128        /* tile size for persistent solver */
#define NT 16         /* tiles per dimension */
#define NTL 256       /* total tiles = blocks */
#define CY 64         /* relax cycles per grid-sync window */

namespace cg = cooperative_groups;

// ---------- shared math (pinned rounding so every pass computes identical fr) ----------
__device__ __forceinline__ float sobel_at(const float* __restrict__ g, int y, int x){
  float a00,a01,a02,a10,a12,a20,a21,a22;
  if (y>0 && y<HH-1 && x>0 && x<WW-1){
    const float* p = g + (size_t)(y-1)*WW + x;
    a00=p[-1]; a01=p[0]; a02=p[1];
    p += WW;   a10=p[-1];          a12=p[1];
    p += WW;   a20=p[-1]; a21=p[0]; a22=p[1];
  } else {
    auto at=[&](int yy,int xx)->float{
      return (yy<0||yy>=HH||xx<0||xx>=WW)?0.0f:g[(size_t)yy*WW+xx];
    };
    a00=at(y-1,x-1); a01=at(y-1,x); a02=at(y-1,x+1);
    a10=at(y,  x-1);                a12=at(y,  x+1);
    a20=at(y+1,x-1); a21=at(y+1,x); a22=at(y+1,x+1);
  }
  float gx = __fadd_rn(__fadd_rn(__fsub_rn(a02,a00), __fmul_rn(2.0f,__fsub_rn(a12,a10))), __fsub_rn(a22,a20));
  float gy = __fadd_rn(__fadd_rn(__fsub_rn(a20,a00), __fmul_rn(2.0f,__fsub_rn(a21,a01))), __fsub_rn(a22,a02));
  return sqrtf(__fadd_rn(__fmul_rn(gx,gx),__fmul_rn(gy,gy)));
}

// ---------- gray ----------
__global__ void gray_kernel(const float* __restrict__ img, float* __restrict__ gray){
  const float* R=img; const float* G=img+NPX; const float* B=img+2*(size_t)NPX;
  for (int i=blockIdx.x*blockDim.x+threadIdx.x; i<NPX; i+=gridDim.x*blockDim.x){
    gray[i] = __fadd_rn(__fadd_rn(__fmul_rn(0.2989f,R[i]),__fmul_rn(0.587f,G[i])),__fmul_rn(0.114f,B[i]));
  }
}

// ---------- sobel once, cached to fr; level-1 histogram fused ----------
__global__ void sobel_hist1(const float* __restrict__ gray, float* __restrict__ fr,
                            unsigned* __restrict__ hist){
  __shared__ unsigned h[4*2048];
  for (int i=threadIdx.x;i<4*2048;i+=blockDim.x) h[i]=0;
  __syncthreads();
  const int rep=(threadIdx.x&3)*2048;
  for (int i=blockIdx.x*blockDim.x+threadIdx.x; i<NPX; i+=gridDim.x*blockDim.x){
    int y=i>>11, x=i&(WW-1);
    float f=sobel_at(gray,y,x);
    fr[i]=f;
    unsigned key=__float_as_uint(f);
    atomicAdd(&h[rep+(key>>21)],1u);
  }
  __syncthreads();
  for (int i=threadIdx.x;i<2048;i+=blockDim.x){
    unsigned s=h[i]+h[i+2048]+h[i+4096]+h[i+6144];
    if (s) atomicAdd(&hist[i],s);
  }
}

__global__ void hist_l2(const float* __restrict__ fr, const unsigned* __restrict__ sel1,
                        unsigned* __restrict__ hist2){
  __shared__ unsigned h[4*2048];
  __shared__ unsigned sb[4];
  if (threadIdx.x<4) sb[threadIdx.x]=sel1[threadIdx.x];
  for (int i=threadIdx.x;i<4*2048;i+=blockDim.x) h[i]=0;
  __syncthreads();
  for (int i=blockIdx.x*blockDim.x+threadIdx.x; i<NPX; i+=gridDim.x*blockDim.x){
    unsigned key=__float_as_uint(fr[i]);
    unsigned b=key>>21, sub=(key>>10)&0x7FFu;
    #pragma unroll
    for (int k=0;k<4;++k) if (b==sb[k]) atomicAdd(&h[k*2048+sub],1u);
  }
  __syncthreads();
  for (int i=threadIdx.x;i<4*2048;i+=blockDim.x){ unsigned s=h[i]; if (s) atomicAdd(&hist2[i],s); }
}

__global__ void hist_l3(const float* __restrict__ fr, const unsigned* __restrict__ sel1,
                        const unsigned* __restrict__ sel2, unsigned* __restrict__ hist3){
  __shared__ unsigned h[4*1024];
  __shared__ unsigned pf[4];
  if (threadIdx.x<4) pf[threadIdx.x]=(sel1[threadIdx.x]<<11)|sel2[threadIdx.x];
  for (int i=threadIdx.x;i<4*1024;i+=blockDim.x) h[i]=0;
  __syncthreads();
  for (int i=blockIdx.x*blockDim.x+threadIdx.x; i<NPX; i+=gridDim.x*blockDim.x){
    unsigned key=__float_as_uint(fr[i]);
    unsigned p22=key>>10, sub=key&0x3FFu;
    #pragma unroll
    for (int k=0;k<4;++k) if (p22==pf[k]) atomicAdd(&h[k*1024+sub],1u);
  }
  __syncthreads();
  for (int i=threadIdx.x;i<4*1024;i+=blockDim.x){ unsigned s=h[i]; if (s) atomicAdd(&hist3[i],s); }
}

// ranks: floor(0.9825*(n-1))=4120902, floor(0.9925*(n-1))=4162845 (and +1 each)
__global__ void scan_l1(const unsigned* __restrict__ hist, unsigned* __restrict__ sel1,
                        unsigned* __restrict__ rem1){
  __shared__ unsigned part[1024];
  const int t=threadIdx.x;
  unsigned a=hist[2*t], b=hist[2*t+1];
  part[t]=a+b; __syncthreads();
  for (int off=1;off<1024;off<<=1){
    unsigned add=(t>=off)?part[t-off]:0u; __syncthreads();
    part[t]+=add; __syncthreads();
  }
  unsigned before=(t>0)?part[t-1]:0u;
  const unsigned R[4]={4120902u,4120903u,4162845u,4162846u};
  unsigned cum=before;
  #pragma unroll
  for (int i=0;i<4;++i) if (R[i]>=cum && R[i]<cum+a){ sel1[i]=2*t;   rem1[i]=R[i]-cum; }
  cum+=a;
  #pragma unroll
  for (int i=0;i<4;++i) if (R[i]>=cum && R[i]<cum+b){ sel1[i]=2*t+1; rem1[i]=R[i]-cum; }
}

__global__ void scan_l2(const unsigned* __restrict__ hist2, const unsigned* __restrict__ rem1,
                        unsigned* __restrict__ sel2, unsigned* __restrict__ rem2){
  __shared__ unsigned part[1024];
  const int t=threadIdx.x;
  for (int i=0;i<4;++i){
    const unsigned* hh=hist2+i*2048;
    unsigned a=hh[2*t], b=hh[2*t+1];
    part[t]=a+b; __syncthreads();
    for (int off=1;off<1024;off<<=1){
      unsigned add=(t>=off)?part[t-off]:0u; __syncthreads();
      part[t]+=add; __syncthreads();
    }
    unsigned before=(t>0)?part[t-1]:0u;
    unsigned r=rem1[i], cum=before;
    if (r>=cum && r<cum+a){ sel2[i]=2*t;   rem2[i]=r-cum; }
    cum+=a;
    if (r>=cum && r<cum+b){ sel2[i]=2*t+1; rem2[i]=r-cum; }
    __syncthreads();
  }
}

__global__ void scan_l3(const unsigned* __restrict__ hist3, const unsigned* __restrict__ sel1,
                        const unsigned* __restrict__ sel2, const unsigned* __restrict__ rem2,
                        float* __restrict__ scal){
  __shared__ unsigned part[1024];
  __shared__ float vals[4];
  const int t=threadIdx.x;
  for (int i=0;i<4;++i){
    unsigned c=hist3[i*1024+t];
    part[t]=c; __syncthreads();
    for (int off=1;off<1024;off<<=1){
      unsigned add=(t>=off)?part[t-off]:0u; __syncthreads();
      part[t]+=add; __syncthreads();
    }
    unsigned before=(t>0)?part[t-1]:0u;
    unsigned r=rem2[i];
    if (r>=before && r<before+c){
      unsigned key=(sel1[i]<<21)|(sel2[i]<<10)|(unsigned)t;
      vals[i]=__uint_as_float(key);
    }
    __syncthreads();
  }
  if (t==0){
    scal[0]=__fadd_rn(__fmul_rn(vals[0],0.25f),__fmul_rn(vals[1],0.75f));
    scal[1]=__fadd_rn(__fmul_rn(vals[2],0.25f),__fmul_rn(vals[3],0.75f));
  }
}

// ---------- markers -> initial costs (fr aliases c1out; per-element read-then-write) ----------
__global__ void init_cost(const float* __restrict__ gray, const float* frbuf,
                          const float* __restrict__ scal,
                          float* c1out, float* __restrict__ c2out){
  const float qlo=scal[0], qhi=scal[1];
  for (int i=blockIdx.x*blockDim.x+threadIdx.x; i<NPX; i+=gridDim.x*blockDim.x){
    float f=frbuf[i];
    float g=gray[i];
    bool m1 = (f<=qlo);
    bool m2 = (!m1) && (f>=qhi);
    c1out[i] = m1 ? g : INFV;
    c2out[i] = m2 ? g : INFV;
  }
}

// ---------- persistent-tile cooperative fixed-point solver (3-barrier cycles) ----------
// clamp composition: f_cur(f_prev(v)) with f=(lo,hi)->min(hi,max(lo,v)):
//   hi' = min(hi_cur, max(lo_cur, hi_prev)); lo' = max(lo_cur, lo_prev)

#define HSCAN_LR(va,vb,gA,gB,hl) do{ \
  float ql_=gA[j], qh_=va[j]; \
  qh_=fminf(vb[j],fmaxf(gB[j],qh_)); ql_=fmaxf(gB[j],ql_); \
  _Pragma("unroll") \
  for (int d_=1;d_<64;d_<<=1){ \
    float pl_=__shfl_up(ql_,(unsigned)d_), ph_=__shfl_up(qh_,(unsigned)d_); \
    if (c>=d_){ qh_=fminf(qh_,fmaxf(ql_,ph_)); ql_=fmaxf(ql_,pl_); } \
  } \
  float E_=fminf(qh_,fmaxf(ql_,(hl))); \
  float In_=__shfl_up(E_,1u); if(c==0) In_=(hl); \
  float na_=fminf(va[j],fmaxf(gA[j],In_)); if(na_<va[j]){va[j]=na_;ch=true;} \
  float nb_=fminf(vb[j],fmaxf(gB[j],na_)); if(nb_<vb[j]){vb[j]=nb_;ch=true;} \
}while(0)

#define HSCAN_RL(va,vb,gA,gB,hr) do{ \
  float ql_=gB[j], qh_=vb[j]; \
  qh_=fminf(va[j],fmaxf(gA[j],qh_)); ql_=fmaxf(gA[j],ql_); \
  _Pragma("unroll") \
  for (int d_=1;d_<64;d_<<=1){ \
    float pl_=__shfl_down(ql_,(unsigned)d_), ph_=__shfl_down(qh_,(unsigned)d_); \
    if (c+d_<64){ qh_=fminf(qh_,fmaxf(ql_,ph_)); ql_=fmaxf(ql_,pl_); } \
  } \
  float E_=fminf(qh_,fmaxf(ql_,(hr))); \
  float In_=__shfl_down(E_,1u); if(c==63) In_=(hr); \
  float nb_=fminf(vb[j],fmaxf(gB[j],In_)); if(nb_<vb[j]){vb[j]=nb_;ch=true;} \
  float na_=fminf(va[j],fmaxf(gA[j],nb_)); if(na_<va[j]){va[j]=na_;ch=true;} \
}while(0)

#define VCOMP_DN(va,gA,Larr,Harr,XX) { float ql_=gA[0], qh_=va[0]; \
  _Pragma("unroll") for (int jj_=1;jj_<8;++jj_){ qh_=fminf(va[jj_],fmaxf(gA[jj_],qh_)); ql_=fmaxf(gA[jj_],ql_);} \
  Larr[w][XX]=ql_; Harr[w][XX]=qh_; }

#define VCOMP_UP(va,gA,Larr,Harr,XX) { float ql_=gA[7], qh_=va[7]; \
  _Pragma("unroll") for (int jj_=6;jj_>=0;--jj_){ qh_=fminf(va[jj_],fmaxf(gA[jj_],qh_)); ql_=fmaxf(gA[jj_],ql_);} \
  Larr[w][XX]=ql_; Harr[w][XX]=qh_; }

#define VAPPLY_DN(va,gA,Larr,XX) { float In_=Larr[w][XX]; \
  _Pragma("unroll") for (int jj_=0;jj_<8;++jj_){ float nv_=fminf(va[jj_],fmaxf(In_,gA[jj_])); if(nv_<va[jj_]){va[jj_]=nv_;ch=true;} In_=nv_; } }

#define VAPPLY_UP(va,gA,Larr,XX) { float In_=Larr[w][XX]; \
  _Pragma("unroll") for (int jj_=7;jj_>=0;--jj_){ float nv_=fminf(va[jj_],fmaxf(In_,gA[jj_])); if(nv_<va[jj_]){va[jj_]=nv_;ch=true;} In_=nv_; } }

#define CHAIN_DN(Harr,Larr,HT) { float E=HALO[HT][x]; \
  _Pragma("unroll") for (int b_=0;b_<16;++b_){ float I=E; E=fminf(Harr[b_][x],fmaxf(Larr[b_][x],I)); Larr[b_][x]=I; } }

#define CHAIN_UP(Harr,Larr,HB) { float E=HALO[HB][x]; \
  _Pragma("unroll") for (int b_=15;b_>=0;--b_){ float I=E; E=fminf(Harr[b_][x],fmaxf(Larr[b_][x],I)); Larr[b_][x]=I; } }

#define HFIELD(va,vb,IHL,IHR) do{ \
  _Pragma("unroll") \
  for (int j=0;j<8;++j){ \
    const int r_=(w<<3)|j; \
    const float hl=HALO[IHL][r_], hr=HALO[IHR][r_]; \
    { float la_=__shfl_up(vb[j],1u); if(c==0) la_=hl; \
      bool p_=__any((fminf(va[j],fmaxf(la_,ga[j]))<va[j])||(fminf(vb[j],fmaxf(va[j],gb[j]))<vb[j])); \
      if (p_){ HSCAN_LR(va,vb,ga,gb,hl); } } \
    { float ra_=__shfl_down(va[j],1u); if(c==63) ra_=hr; \
      bool p_=__any((fminf(vb[j],fmaxf(ra_,gb[j]))<vb[j])||(fminf(va[j],fmaxf(vb[j],ga[j]))<va[j])); \
      if (p_){ HSCAN_RL(va,vb,ga,gb,hr); } } \
  } \
}while(0)

#define ASTORE(p,v) __hip_atomic_store((p),(v),__ATOMIC_RELAXED,__HIP_MEMORY_SCOPE_AGENT)

__global__ void __launch_bounds__(1024,4)
ws_solve(float* __restrict__ c1g, const float* __restrict__ grayg, float* outg,
         int* __restrict__ flagIt)
{
  __shared__ float DNL1[16][128], DNH1[16][128], DNL2[16][128], DNH2[16][128];
  __shared__ float UPL1[16][128], UPH1[16][128], UPL2[16][128], UPH2[16][128];
  __shared__ float HALO[8][128];   // 0 Ht1,1 Ht2,2 Hb1,3 Hb2,4 Hl1,5 Hl2,6 Hr1,7 Hr2
  __shared__ int F1[3], F2[3];
  __shared__ int wflag;
  cg::grid_group grid = cg::this_grid();
  const int tid=threadIdx.x, w=tid>>6, c=tid&63;
  const int tile=blockIdx.x, ty=tile>>4, tx=tile&15;
  const int by=ty*TS, bx=tx*TS, x0=c<<1;
  float* EB1=outg;
  float* EB2=outg+(NTL*4*128);

  // this thread's halo poll slot (1024 threads <-> 8 arrays x 128 entries)
  const int hx=tid&127, harr=tid>>7;
  const float* hsrc=nullptr;
  {
    const float* EB=(harr&1)?EB2:EB1;
    switch(harr>>1){
      case 0: if (ty>0)    hsrc=EB+((tile-NT)*4+1)*128+hx; break;
      case 1: if (ty<NT-1) hsrc=EB+((tile+NT)*4+0)*128+hx; break;
      case 2: if (tx>0)    hsrc=EB+((tile-1)*4+3)*128+hx;  break;
      default:if (tx<NT-1) hsrc=EB+((tile+1)*4+2)*128+hx;  break;
    }
  }

  float v1a[8],v1b[8],v2a[8],v2b[8],ga[8],gb[8];
  {
    size_t base=(size_t)(by+(w<<3))*WW + bx + x0;
    #pragma unroll
    for (int j=0;j<8;++j){
      float2 t1=*(const float2*)(c1g+base);
      float2 t2=*(const float2*)(outg+base);   // c2 initial lives in d_out
      float2 tg=*(const float2*)(grayg+base);
      v1a[j]=t1.x; v1b[j]=t1.y; v2a[j]=t2.x; v2b[j]=t2.y; ga[j]=tg.x; gb[j]=tg.y;
      base+=(size_t)WW;
    }
  }
  grid.sync();   // all c2 loads complete before edge buffers overwrite d_out

  // pre-publish initial edges so halos are live from the first cycle
  if (w==0){ const int eb=(tile*4+0)*128;
    ASTORE(EB1+eb+x0,v1a[0]); ASTORE(EB1+eb+x0+1,v1b[0]);
    ASTORE(EB2+eb+x0,v2a[0]); ASTORE(EB2+eb+x0+1,v2b[0]); }
  if (w==15){ const int eb=(tile*4+1)*128;
    ASTORE(EB1+eb+x0,v1a[7]); ASTORE(EB1+eb+x0+1,v1b[7]);
    ASTORE(EB2+eb+x0,v2a[7]); ASTORE(EB2+eb+x0+1,v2b[7]); }
  if (c==0){ const int eb=(tile*4+2)*128+(w<<3);
    #pragma unroll
    for (int j=0;j<8;++j){ ASTORE(EB1+eb+j,v1a[j]); ASTORE(EB2+eb+j,v2a[j]); } }
  if (c==63){ const int eb=(tile*4+3)*128+(w<<3);
    #pragma unroll
    for (int j=0;j<8;++j){ ASTORE(EB1+eb+j,v1b[j]); ASTORE(EB2+eb+j,v2b[j]); } }
  HALO[harr][hx]=INFV;
  if (tid==0){ F1[0]=1;F2[0]=1;F1[1]=0;F2[1]=0;F1[2]=0;F2[2]=0; wflag=0; }
  float hv=0.0f; bool hvok=false;
  __threadfence();
  grid.sync();

  for (int win=0; win<96; ++win){
    for (int cyc=0; cyc<CY; ++cyc){
      const int gc=(win<<6)|cyc;
      const int cur=gc%3, nxt=(gc+1)%3, old=(gc+2)%3;
      const int r1=F1[cur], r2=F2[cur];
      if (tid==0){ F1[old]=0; F2[old]=0; }
      if (!(r1|r2)){
        // quiet cycle: consume last poll (batched), issue next poll
        if (hsrc){
          if (hvok && hv<HALO[harr][hx]){
            HALO[harr][hx]=hv;
            if (harr&1) F2[nxt]=1; else F1[nxt]=1;
          }
          hv=__hip_atomic_load(hsrc,__ATOMIC_RELAXED,__HIP_MEMORY_SCOPE_AGENT);
          hvok=true;
        }
        __syncthreads();
        continue;
      }
      // ---- P1: band compose, both directions, dirty fields ----
      if (r1){
        VCOMP_DN(v1a,ga,DNL1,DNH1,x0) VCOMP_DN(v1b,gb,DNL1,DNH1,x0+1)
        VCOMP_UP(v1a,ga,UPL1,UPH1,x0) VCOMP_UP(v1b,gb,UPL1,UPH1,x0+1)
      }
      if (r2){
        VCOMP_DN(v2a,ga,DNL2,DNH2,x0) VCOMP_DN(v2b,gb,DNL2,DNH2,x0+1)
        VCOMP_UP(v2a,ga,UPL2,UPH2,x0) VCOMP_UP(v2b,gb,UPL2,UPH2,x0+1)
      }
      __syncthreads();
      // ---- P2: cross-band chains (8 waves, 1 col/lane) ----
      if (w<8){
        const int x=((w&1)<<6)|c;
        const bool go = (w>>2) ? (r2!=0) : (r1!=0);
        if (go){
          switch(w>>1){
            case 0: CHAIN_DN(DNH1,DNL1,0) break;
            case 1: CHAIN_UP(UPH1,UPL1,2) break;
            case 2: CHAIN_DN(DNH2,DNL2,1) break;
            default:CHAIN_UP(UPH2,UPL2,3) break;
          }
        }
      }
      __syncthreads();
      // ---- P3: vertical apply + horizontal scans + flags + publish ----
      bool chf1=false, chf2=false;
      if (r1){ bool ch=false;
        VAPPLY_DN(v1a,ga,DNL1,x0) VAPPLY_DN(v1b,gb,DNL1,x0+1)
        VAPPLY_UP(v1a,ga,UPL1,x0) VAPPLY_UP(v1b,gb,UPL1,x0+1)
        HFIELD(v1a,v1b,4,6);
        if (ch){ F1[nxt]=1; wflag=1; chf1=true; }
      }
      if (r2){ bool ch=false;
        VAPPLY_DN(v2a,ga,DNL2,x0) VAPPLY_DN(v2b,gb,DNL2,x0+1)
        VAPPLY_UP(v2a,ga,UPL2,x0) VAPPLY_UP(v2b,gb,UPL2,x0+1)
        HFIELD(v2a,v2b,5,7);
        if (ch){ F2[nxt]=1; wflag=1; chf2=true; }
      }
      if (chf1|chf2){
        if (w==0){ const int eb=(tile*4+0)*128;
          if(chf1){ ASTORE(EB1+eb+x0,v1a[0]); ASTORE(EB1+eb+x0+1,v1b[0]); }
          if(chf2){ ASTORE(EB2+eb+x0,v2a[0]); ASTORE(EB2+eb+x0+1,v2b[0]); } }
        if (w==15){ const int eb=(tile*4+1)*128;
          if(chf1){ ASTORE(EB1+eb+x0,v1a[7]); ASTORE(EB1+eb+x0+1,v1b[7]); }
          if(chf2){ ASTORE(EB2+eb+x0,v2a[7]); ASTORE(EB2+eb+x0+1,v2b[7]); } }
        if (c==0){ const int eb=(tile*4+2)*128+(w<<3);
          #pragma unroll
          for (int j=0;j<8;++j){ if(chf1)ASTORE(EB1+eb+j,v1a[j]); if(chf2)ASTORE(EB2+eb+j,v2a[j]); } }
        if (c==63){ const int eb=(tile*4+3)*128+(w<<3);
          #pragma unroll
          for (int j=0;j<8;++j){ if(chf1)ASTORE(EB1+eb+j,v1b[j]); if(chf2)ASTORE(EB2+eb+j,v2b[j]); } }
      }
      __syncthreads();
    }
    // window end: termination handshake
    if (tid==0 && wflag) atomicMax(flagIt,win+1);
    __threadfence();
    grid.sync();
    int fv=__hip_atomic_load(flagIt,__ATOMIC_RELAXED,__HIP_MEMORY_SCOPE_AGENT);
    if (fv<=win) break;   // a full window with zero changes anywhere -> fixed point
    if (tid==0) wflag=0;
    __syncthreads();
  }
  // fused label output: out = (c2 < c1) ? 1 : 0
  {
    size_t base=(size_t)(by+(w<<3))*WW + bx + x0;
    #pragma unroll
    for (int j=0;j<8;++j){
      float2 o; o.x=(v2a[j]<v1a[j])?1.0f:0.0f; o.y=(v2b[j]<v1b[j])?1.0f:0.0f;
      *(float2*)(outg+base)=o;
      base+=(size_t)WW;
    }
  }
}

extern "C" void kernel_launch(void* const* d_in, const int* in_sizes, int n_in,
                              void* d_out, int out_size, void* d_ws, size_t ws_size,
                              hipStream_t stream)
{
  const float* img=(const float*)d_in[0];
  float* out=(float*)d_out;
  char* wsb=(char*)d_ws;
  float* gray=(float*)wsb;
  float* c1  =(float*)(wsb + (size_t)NPX*4);   // doubles as fr cache before init_cost
  unsigned* meta=(unsigned*)(wsb + (size_t)NPX*8);
  float* c2 = out;   // c2 initial state lives in d_out (fully rewritten each launch)

  unsigned* hist1=meta;            // 2048
  unsigned* hist2=meta+2048;       // 4*2048
  unsigned* hist3=meta+10240;      // 4*1024
  unsigned* sel1 =meta+14336;
  unsigned* rem1 =meta+14340;
  unsigned* sel2 =meta+14344;
  unsigned* rem2 =meta+14348;
  float*    scal =(float*)(meta+14352);   // 2
  int*      flagIt=(int*)(meta+14354);    // 1  -> total 14355 u32

  hipMemsetAsync(meta, 0, 14355*sizeof(unsigned), stream);
  hipLaunchKernelGGL(gray_kernel, dim3(4096), dim3(256), 0, stream, img, gray);
  hipLaunchKernelGGL(sobel_hist1, dim3(1024), dim3(256), 0, stream, gray, c1, hist1);
  hipLaunchKernelGGL(scan_l1, dim3(1), dim3(1024), 0, stream, hist1, sel1, rem1);
  hipLaunchKernelGGL(hist_l2, dim3(1024), dim3(256), 0, stream, c1, sel1, hist2);
  hipLaunchKernelGGL(scan_l2, dim3(1), dim3(1024), 0, stream, hist2, rem1, sel2, rem2);
  hipLaunchKernelGGL(hist_l3, dim3(1024), dim3(256), 0, stream, c1, sel1, sel2, hist3);
  hipLaunchKernelGGL(scan_l3, dim3(1), dim3(1024), 0, stream, hist3, sel1, sel2, rem2, scal);
  hipLaunchKernelGGL(init_cost, dim3(4096), dim3(256), 0, stream, gray, c1, scal, c1, c2);

  void* args[]={ (void*)&c1,(void*)&gray,(void*)&out,(void*)&flagIt };
  (void)hipLaunchCooperativeKernel(ws_solve, dim3(NTL), dim3(1024), args, 0, stream);
}

// Round 6
// 1139.288 us; speedup vs baseline: 1.3032x; 1.3032x over previous
//
#include <hip/hip_runtime.h>
#include <hip/hip_cooperative_groups.h>

#define HH 2048
#define WW 2048
#define NPX (HH*WW)
#define INFV 1e30f
#define TS 128        /* tile size for persistent solver */
#define NT 16         /* tiles per dimension */
#define NTL 256       /* total tiles = blocks */
#define CY 64         /* relax cycles per grid-sync window */

namespace cg = cooperative_groups;

// raw barrier: LDS-drain only; outstanding global (halo poll) loads stay in flight
__device__ __forceinline__ void BARL(){
  __builtin_amdgcn_sched_barrier(0);
  asm volatile("s_waitcnt lgkmcnt(0)" ::: "memory");
  __builtin_amdgcn_s_barrier();
  __builtin_amdgcn_sched_barrier(0);
}

// ---------- shared math (pinned rounding so every pass computes identical fr) ----------
__device__ __forceinline__ float sobel_at(const float* __restrict__ g, int y, int x){
  float a00,a01,a02,a10,a12,a20,a21,a22;
  if (y>0 && y<HH-1 && x>0 && x<WW-1){
    const float* p = g + (size_t)(y-1)*WW + x;
    a00=p[-1]; a01=p[0]; a02=p[1];
    p += WW;   a10=p[-1];          a12=p[1];
    p += WW;   a20=p[-1]; a21=p[0]; a22=p[1];
  } else {
    auto at=[&](int yy,int xx)->float{
      return (yy<0||yy>=HH||xx<0||xx>=WW)?0.0f:g[(size_t)yy*WW+xx];
    };
    a00=at(y-1,x-1); a01=at(y-1,x); a02=at(y-1,x+1);
    a10=at(y,  x-1);                a12=at(y,  x+1);
    a20=at(y+1,x-1); a21=at(y+1,x); a22=at(y+1,x+1);
  }
  float gx = __fadd_rn(__fadd_rn(__fsub_rn(a02,a00), __fmul_rn(2.0f,__fsub_rn(a12,a10))), __fsub_rn(a22,a20));
  float gy = __fadd_rn(__fadd_rn(__fsub_rn(a20,a00), __fmul_rn(2.0f,__fsub_rn(a21,a01))), __fsub_rn(a22,a02));
  return sqrtf(__fadd_rn(__fmul_rn(gx,gx),__fmul_rn(gy,gy)));
}

// ---------- gray ----------
__global__ void gray_kernel(const float* __restrict__ img, float* __restrict__ gray){
  const float* R=img; const float* G=img+NPX; const float* B=img+2*(size_t)NPX;
  for (int i=blockIdx.x*blockDim.x+threadIdx.x; i<NPX; i+=gridDim.x*blockDim.x){
    gray[i] = __fadd_rn(__fadd_rn(__fmul_rn(0.2989f,R[i]),__fmul_rn(0.587f,G[i])),__fmul_rn(0.114f,B[i]));
  }
}

// ---------- sobel once, cached to fr; level-1 histogram fused ----------
__global__ void sobel_hist1(const float* __restrict__ gray, float* __restrict__ fr,
                            unsigned* __restrict__ hist){
  __shared__ unsigned h[4*2048];
  for (int i=threadIdx.x;i<4*2048;i+=blockDim.x) h[i]=0;
  __syncthreads();
  const int rep=(threadIdx.x&3)*2048;
  for (int i=blockIdx.x*blockDim.x+threadIdx.x; i<NPX; i+=gridDim.x*blockDim.x){
    int y=i>>11, x=i&(WW-1);
    float f=sobel_at(gray,y,x);
    fr[i]=f;
    unsigned key=__float_as_uint(f);
    atomicAdd(&h[rep+(key>>21)],1u);
  }
  __syncthreads();
  for (int i=threadIdx.x;i<2048;i+=blockDim.x){
    unsigned s=h[i]+h[i+2048]+h[i+4096]+h[i+6144];
    if (s) atomicAdd(&hist[i],s);
  }
}

__global__ void hist_l2(const float* __restrict__ fr, const unsigned* __restrict__ sel1,
                        unsigned* __restrict__ hist2){
  __shared__ unsigned h[4*2048];
  __shared__ unsigned sb[4];
  if (threadIdx.x<4) sb[threadIdx.x]=sel1[threadIdx.x];
  for (int i=threadIdx.x;i<4*2048;i+=blockDim.x) h[i]=0;
  __syncthreads();
  for (int i=blockIdx.x*blockDim.x+threadIdx.x; i<NPX; i+=gridDim.x*blockDim.x){
    unsigned key=__float_as_uint(fr[i]);
    unsigned b=key>>21, sub=(key>>10)&0x7FFu;
    #pragma unroll
    for (int k=0;k<4;++k) if (b==sb[k]) atomicAdd(&h[k*2048+sub],1u);
  }
  __syncthreads();
  for (int i=threadIdx.x;i<4*2048;i+=blockDim.x){ unsigned s=h[i]; if (s) atomicAdd(&hist2[i],s); }
}

__global__ void hist_l3(const float* __restrict__ fr, const unsigned* __restrict__ sel1,
                        const unsigned* __restrict__ sel2, unsigned* __restrict__ hist3){
  __shared__ unsigned h[4*1024];
  __shared__ unsigned pf[4];
  if (threadIdx.x<4) pf[threadIdx.x]=(sel1[threadIdx.x]<<11)|sel2[threadIdx.x];
  for (int i=threadIdx.x;i<4*1024;i+=blockDim.x) h[i]=0;
  __syncthreads();
  for (int i=blockIdx.x*blockDim.x+threadIdx.x; i<NPX; i+=gridDim.x*blockDim.x){
    unsigned key=__float_as_uint(fr[i]);
    unsigned p22=key>>10, sub=key&0x3FFu;
    #pragma unroll
    for (int k=0;k<4;++k) if (p22==pf[k]) atomicAdd(&h[k*1024+sub],1u);
  }
  __syncthreads();
  for (int i=threadIdx.x;i<4*1024;i+=blockDim.x){ unsigned s=h[i]; if (s) atomicAdd(&hist3[i],s); }
}

// ranks: floor(0.9825*(n-1))=4120902, floor(0.9925*(n-1))=4162845 (and +1 each)
__global__ void scan_l1(const unsigned* __restrict__ hist, unsigned* __restrict__ sel1,
                        unsigned* __restrict__ rem1){
  __shared__ unsigned part[1024];
  const int t=threadIdx.x;
  unsigned a=hist[2*t], b=hist[2*t+1];
  part[t]=a+b; __syncthreads();
  for (int off=1;off<1024;off<<=1){
    unsigned add=(t>=off)?part[t-off]:0u; __syncthreads();
    part[t]+=add; __syncthreads();
  }
  unsigned before=(t>0)?part[t-1]:0u;
  const unsigned R[4]={4120902u,4120903u,4162845u,4162846u};
  unsigned cum=before;
  #pragma unroll
  for (int i=0;i<4;++i) if (R[i]>=cum && R[i]<cum+a){ sel1[i]=2*t;   rem1[i]=R[i]-cum; }
  cum+=a;
  #pragma unroll
  for (int i=0;i<4;++i) if (R[i]>=cum && R[i]<cum+b){ sel1[i]=2*t+1; rem1[i]=R[i]-cum; }
}

__global__ void scan_l2(const unsigned* __restrict__ hist2, const unsigned* __restrict__ rem1,
                        unsigned* __restrict__ sel2, unsigned* __restrict__ rem2){
  __shared__ unsigned part[1024];
  const int t=threadIdx.x;
  for (int i=0;i<4;++i){
    const unsigned* hh=hist2+i*2048;
    unsigned a=hh[2*t], b=hh[2*t+1];
    part[t]=a+b; __syncthreads();
    for (int off=1;off<1024;off<<=1){
      unsigned add=(t>=off)?part[t-off]:0u; __syncthreads();
      part[t]+=add; __syncthreads();
    }
    unsigned before=(t>0)?part[t-1]:0u;
    unsigned r=rem1[i], cum=before;
    if (r>=cum && r<cum+a){ sel2[i]=2*t;   rem2[i]=r-cum; }
    cum+=a;
    if (r>=cum && r<cum+b){ sel2[i]=2*t+1; rem2[i]=r-cum; }
    __syncthreads();
  }
}

__global__ void scan_l3(const unsigned* __restrict__ hist3, const unsigned* __restrict__ sel1,
                        const unsigned* __restrict__ sel2, const unsigned* __restrict__ rem2,
                        float* __restrict__ scal){
  __shared__ unsigned part[1024];
  __shared__ float vals[4];
  const int t=threadIdx.x;
  for (int i=0;i<4;++i){
    unsigned c=hist3[i*1024+t];
    part[t]=c; __syncthreads();
    for (int off=1;off<1024;off<<=1){
      unsigned add=(t>=off)?part[t-off]:0u; __syncthreads();
      part[t]+=add; __syncthreads();
    }
    unsigned before=(t>0)?part[t-1]:0u;
    unsigned r=rem2[i];
    if (r>=before && r<before+c){
      unsigned key=(sel1[i]<<21)|(sel2[i]<<10)|(unsigned)t;
      vals[i]=__uint_as_float(key);
    }
    __syncthreads();
  }
  if (t==0){
    scal[0]=__fadd_rn(__fmul_rn(vals[0],0.25f),__fmul_rn(vals[1],0.75f));
    scal[1]=__fadd_rn(__fmul_rn(vals[2],0.25f),__fmul_rn(vals[3],0.75f));
  }
}

// ---------- markers -> initial costs (fr aliases c1out; per-element read-then-write) ----------
__global__ void init_cost(const float* __restrict__ gray, const float* frbuf,
                          const float* __restrict__ scal,
                          float* c1out, float* __restrict__ c2out){
  const float qlo=scal[0], qhi=scal[1];
  for (int i=blockIdx.x*blockDim.x+threadIdx.x; i<NPX; i+=gridDim.x*blockDim.x){
    float f=frbuf[i];
    float g=gray[i];
    bool m1 = (f<=qlo);
    bool m2 = (!m1) && (f>=qhi);
    c1out[i] = m1 ? g : INFV;
    c2out[i] = m2 ? g : INFV;
  }
}

// ---------- persistent-tile cooperative fixed-point solver ----------
// clamp composition: f_cur(f_prev(v)) with f=(lo,hi)->min(hi,max(lo,v)):
//   hi' = min(hi_cur, max(lo_cur, hi_prev)); lo' = max(lo_cur, lo_prev)

#define HSCAN_LR(va,vb,gA,gB,hl) do{ \
  float ql_=gA[j], qh_=va[j]; \
  qh_=fminf(vb[j],fmaxf(gB[j],qh_)); ql_=fmaxf(gB[j],ql_); \
  _Pragma("unroll") \
  for (int d_=1;d_<64;d_<<=1){ \
    float pl_=__shfl_up(ql_,(unsigned)d_), ph_=__shfl_up(qh_,(unsigned)d_); \
    if (c>=d_){ qh_=fminf(qh_,fmaxf(ql_,ph_)); ql_=fmaxf(ql_,pl_); } \
  } \
  float E_=fminf(qh_,fmaxf(ql_,(hl))); \
  float In_=__shfl_up(E_,1u); if(c==0) In_=(hl); \
  float na_=fminf(va[j],fmaxf(gA[j],In_)); if(na_<va[j]){va[j]=na_;ch=true;} \
  float nb_=fminf(vb[j],fmaxf(gB[j],na_)); if(nb_<vb[j]){vb[j]=nb_;ch=true;} \
}while(0)

#define HSCAN_RL(va,vb,gA,gB,hr) do{ \
  float ql_=gB[j], qh_=vb[j]; \
  qh_=fminf(va[j],fmaxf(gA[j],qh_)); ql_=fmaxf(gA[j],ql_); \
  _Pragma("unroll") \
  for (int d_=1;d_<64;d_<<=1){ \
    float pl_=__shfl_down(ql_,(unsigned)d_), ph_=__shfl_down(qh_,(unsigned)d_); \
    if (c+d_<64){ qh_=fminf(qh_,fmaxf(ql_,ph_)); ql_=fmaxf(ql_,pl_); } \
  } \
  float E_=fminf(qh_,fmaxf(ql_,(hr))); \
  float In_=__shfl_down(E_,1u); if(c==63) In_=(hr); \
  float nb_=fminf(vb[j],fmaxf(gB[j],In_)); if(nb_<vb[j]){vb[j]=nb_;ch=true;} \
  float na_=fminf(va[j],fmaxf(gA[j],nb_)); if(na_<va[j]){va[j]=na_;ch=true;} \
}while(0)

#define VCOMP_DN(va,gA,Larr,Harr,XX) { float ql_=gA[0], qh_=va[0]; \
  _Pragma("unroll") for (int jj_=1;jj_<8;++jj_){ qh_=fminf(va[jj_],fmaxf(gA[jj_],qh_)); ql_=fmaxf(gA[jj_],ql_);} \
  Larr[w][XX]=ql_; Harr[w][XX]=qh_; }

#define VCOMP_UP(va,gA,Larr,Harr,XX) { float ql_=gA[7], qh_=va[7]; \
  _Pragma("unroll") for (int jj_=6;jj_>=0;--jj_){ qh_=fminf(va[jj_],fmaxf(gA[jj_],qh_)); ql_=fmaxf(gA[jj_],ql_);} \
  Larr[w][XX]=ql_; Harr[w][XX]=qh_; }

#define VAPPLY_DN(va,gA,Larr,XX) { float In_=Larr[w][XX]; \
  _Pragma("unroll") for (int jj_=0;jj_<8;++jj_){ float nv_=fminf(va[jj_],fmaxf(In_,gA[jj_])); if(nv_<va[jj_]){va[jj_]=nv_;ch=true;} In_=nv_; } }

#define VAPPLY_UP(va,gA,Larr,XX) { float In_=Larr[w][XX]; \
  _Pragma("unroll") for (int jj_=7;jj_>=0;--jj_){ float nv_=fminf(va[jj_],fmaxf(In_,gA[jj_])); if(nv_<va[jj_]){va[jj_]=nv_;ch=true;} In_=nv_; } }

#define CHAIN_DN(Harr,Larr,HT) { float E=HALO[HT][x]; \
  _Pragma("unroll") for (int b_=0;b_<16;++b_){ float I=E; E=fminf(Harr[b_][x],fmaxf(Larr[b_][x],I)); Larr[b_][x]=I; } }

#define CHAIN_UP(Harr,Larr,HB) { float E=HALO[HB][x]; \
  _Pragma("unroll") for (int b_=15;b_>=0;--b_){ float I=E; E=fminf(Harr[b_][x],fmaxf(Larr[b_][x],I)); Larr[b_][x]=I; } }

#define HFIELD(va,vb,IHL,IHR) do{ \
  _Pragma("unroll") \
  for (int j=0;j<8;++j){ \
    const int r_=(w<<3)|j; \
    const float hl=HALO[IHL][r_], hr=HALO[IHR][r_]; \
    { float la_=__shfl_up(vb[j],1u); if(c==0) la_=hl; \
      bool p_=__any((fminf(va[j],fmaxf(la_,ga[j]))<va[j])||(fminf(vb[j],fmaxf(va[j],gb[j]))<vb[j])); \
      if (p_){ HSCAN_LR(va,vb,ga,gb,hl); } } \
    { float ra_=__shfl_down(va[j],1u); if(c==63) ra_=hr; \
      bool p_=__any((fminf(vb[j],fmaxf(ra_,gb[j]))<vb[j])||(fminf(va[j],fmaxf(vb[j],ga[j]))<va[j])); \
      if (p_){ HSCAN_RL(va,vb,ga,gb,hr); } } \
  } \
}while(0)

#define ASTORE(p,v) __hip_atomic_store((p),(v),__ATOMIC_RELAXED,__HIP_MEMORY_SCOPE_AGENT)
#define ALOAD(p)    __hip_atomic_load((p),__ATOMIC_RELAXED,__HIP_MEMORY_SCOPE_AGENT)

__global__ void __launch_bounds__(1024,4)
ws_solve(float* __restrict__ c1g, const float* __restrict__ grayg, float* outg,
         int* __restrict__ flagIt)
{
  __shared__ float DNL1[16][128], DNH1[16][128], DNL2[16][128], DNH2[16][128];
  __shared__ float UPL1[16][128], UPH1[16][128], UPL2[16][128], UPH2[16][128];
  __shared__ float HALO[8][128];   // 0 Ht1,1 Ht2,2 Hb1,3 Hb2,4 Hl1,5 Hl2,6 Hr1,7 Hr2
  __shared__ int F1[3], F2[3];
  __shared__ int wflag;
  cg::grid_group grid = cg::this_grid();
  const int tid=threadIdx.x, w=tid>>6, c=tid&63;
  // XCD-chunked tile mapping: each of 8 XCDs (blockIdx%8, assuming round-robin)
  // owns a 4x8-tile region so most neighbor edges are same-L2. Perf heuristic only.
  const int xcd=blockIdx.x&7, idx=blockIdx.x>>3;
  const int tx=((xcd&3)<<2)|(idx&3), ty=((xcd>>2)<<3)|(idx>>2);
  const int tile=ty*NT+tx;
  const int by=ty*TS, bx=tx*TS, x0=c<<1;
  float* EB1=outg;
  float* EB2=outg+(NTL*4*128);

  // this thread's halo poll slot (1024 threads <-> 8 arrays x 128 entries)
  const int hx=tid&127, harr=tid>>7;
  const float* hsrc=nullptr;
  {
    const float* EB=(harr&1)?EB2:EB1;
    switch(harr>>1){
      case 0: if (ty>0)    hsrc=EB+((tile-NT)*4+1)*128+hx; break;
      case 1: if (ty<NT-1) hsrc=EB+((tile+NT)*4+0)*128+hx; break;
      case 2: if (tx>0)    hsrc=EB+((tile-1)*4+3)*128+hx;  break;
      default:if (tx<NT-1) hsrc=EB+((tile+1)*4+2)*128+hx;  break;
    }
  }

  float v1a[8],v1b[8],v2a[8],v2b[8],ga[8],gb[8];
  {
    size_t base=(size_t)(by+(w<<3))*WW + bx + x0;
    #pragma unroll
    for (int j=0;j<8;++j){
      float2 t1=*(const float2*)(c1g+base);
      float2 t2=*(const float2*)(outg+base);   // c2 initial lives in d_out
      float2 tg=*(const float2*)(grayg+base);
      v1a[j]=t1.x; v1b[j]=t1.y; v2a[j]=t2.x; v2b[j]=t2.y; ga[j]=tg.x; gb[j]=tg.y;
      base+=(size_t)WW;
    }
  }
  grid.sync();   // all c2 loads complete before edge buffers overwrite d_out

  // pre-publish initial edges so halos are live from the first cycle
  if (w==0){ const int eb=(tile*4+0)*128;
    ASTORE(EB1+eb+x0,v1a[0]); ASTORE(EB1+eb+x0+1,v1b[0]);
    ASTORE(EB2+eb+x0,v2a[0]); ASTORE(EB2+eb+x0+1,v2b[0]); }
  if (w==15){ const int eb=(tile*4+1)*128;
    ASTORE(EB1+eb+x0,v1a[7]); ASTORE(EB1+eb+x0+1,v1b[7]);
    ASTORE(EB2+eb+x0,v2a[7]); ASTORE(EB2+eb+x0+1,v2b[7]); }
  if (c==0){ const int eb=(tile*4+2)*128+(w<<3);
    #pragma unroll
    for (int j=0;j<8;++j){ ASTORE(EB1+eb+j,v1a[j]); ASTORE(EB2+eb+j,v2a[j]); } }
  if (c==63){ const int eb=(tile*4+3)*128+(w<<3);
    #pragma unroll
    for (int j=0;j<8;++j){ ASTORE(EB1+eb+j,v1b[j]); ASTORE(EB2+eb+j,v2b[j]); } }
  HALO[harr][hx]=INFV;
  if (tid==0){ F1[0]=1;F2[0]=1;F1[1]=0;F2[1]=0;F1[2]=0;F2[2]=0; wflag=0; }
  float hv=0.0f; bool hvok=false;
  __threadfence();
  grid.sync();

  for (int win=0; win<96; ++win){
    for (int cyc=0; cyc<CY; ++cyc){
      const int gc=(win<<6)|cyc;
      const int cur=gc%3, nxt=(gc+1)%3, old=(gc+2)%3;
      // consume previous poll, reissue (every cycle; load floats across raw barriers)
      if (hsrc){
        if (hvok && hv<HALO[harr][hx]){
          HALO[harr][hx]=hv;
          if (harr&1) F2[nxt]=1; else F1[nxt]=1;
        }
        hv=ALOAD(hsrc); hvok=true;
      }
      const int r1=F1[cur], r2=F2[cur];
      if (tid==0){ F1[old]=0; F2[old]=0; }
      if (!(r1|r2)){ BARL(); continue; }
      // ---- P1: band compose, both directions, dirty fields ----
      if (r1){
        VCOMP_DN(v1a,ga,DNL1,DNH1,x0) VCOMP_DN(v1b,gb,DNL1,DNH1,x0+1)
        VCOMP_UP(v1a,ga,UPL1,UPH1,x0) VCOMP_UP(v1b,gb,UPL1,UPH1,x0+1)
      }
      if (r2){
        VCOMP_DN(v2a,ga,DNL2,DNH2,x0) VCOMP_DN(v2b,gb,DNL2,DNH2,x0+1)
        VCOMP_UP(v2a,ga,UPL2,UPH2,x0) VCOMP_UP(v2b,gb,UPL2,UPH2,x0+1)
      }
      BARL();
      // ---- P2: cross-band chains (8 waves, 1 col/lane) ----
      if (w<8){
        const int x=((w&1)<<6)|c;
        const bool go = (w>>2) ? (r2!=0) : (r1!=0);
        if (go){
          switch(w>>1){
            case 0: CHAIN_DN(DNH1,DNL1,0) break;
            case 1: CHAIN_UP(UPH1,UPL1,2) break;
            case 2: CHAIN_DN(DNH2,DNL2,1) break;
            default:CHAIN_UP(UPH2,UPL2,3) break;
          }
        }
      }
      BARL();
      // ---- P3: vertical apply + horizontal scans + flags + publish ----
      bool chf1=false, chf2=false;
      if (r1){ bool ch=false;
        VAPPLY_DN(v1a,ga,DNL1,x0) VAPPLY_DN(v1b,gb,DNL1,x0+1)
        VAPPLY_UP(v1a,ga,UPL1,x0) VAPPLY_UP(v1b,gb,UPL1,x0+1)
        HFIELD(v1a,v1b,4,6);
        if (ch){ F1[nxt]=1; wflag=1; chf1=true; }
      }
      if (r2){ bool ch=false;
        VAPPLY_DN(v2a,ga,DNL2,x0) VAPPLY_DN(v2b,gb,DNL2,x0+1)
        VAPPLY_UP(v2a,ga,UPL2,x0) VAPPLY_UP(v2b,gb,UPL2,x0+1)
        HFIELD(v2a,v2b,5,7);
        if (ch){ F2[nxt]=1; wflag=1; chf2=true; }
      }
      if (chf1|chf2){
        if (w==0){ const int eb=(tile*4+0)*128;
          if(chf1){ ASTORE(EB1+eb+x0,v1a[0]); ASTORE(EB1+eb+x0+1,v1b[0]); }
          if(chf2){ ASTORE(EB2+eb+x0,v2a[0]); ASTORE(EB2+eb+x0+1,v2b[0]); } }
        if (w==15){ const int eb=(tile*4+1)*128;
          if(chf1){ ASTORE(EB1+eb+x0,v1a[7]); ASTORE(EB1+eb+x0+1,v1b[7]); }
          if(chf2){ ASTORE(EB2+eb+x0,v2a[7]); ASTORE(EB2+eb+x0+1,v2b[7]); } }
        if (c==0){ const int eb=(tile*4+2)*128+(w<<3);
          #pragma unroll
          for (int j=0;j<8;++j){ if(chf1)ASTORE(EB1+eb+j,v1a[j]); if(chf2)ASTORE(EB2+eb+j,v2a[j]); } }
        if (c==63){ const int eb=(tile*4+3)*128+(w<<3);
          #pragma unroll
          for (int j=0;j<8;++j){ if(chf1)ASTORE(EB1+eb+j,v1b[j]); if(chf2)ASTORE(EB2+eb+j,v2b[j]); } }
      }
      BARL();
    }
    // window end: termination handshake
    if (tid==0 && wflag) atomicMax(flagIt,win+1);
    __threadfence();
    grid.sync();
    int fv=ALOAD(flagIt);
    if (fv<=win) break;   // a full window with zero changes anywhere -> fixed point
    if (tid==0) wflag=0;
    __syncthreads();
  }
  // fused label output: out = (c2 < c1) ? 1 : 0
  {
    size_t base=(size_t)(by+(w<<3))*WW + bx + x0;
    #pragma unroll
    for (int j=0;j<8;++j){
      float2 o; o.x=(v2a[j]<v1a[j])?1.0f:0.0f; o.y=(v2b[j]<v1b[j])?1.0f:0.0f;
      *(float2*)(outg+base)=o;
      base+=(size_t)WW;
    }
  }
}

extern "C" void kernel_launch(void* const* d_in, const int* in_sizes, int n_in,
                              void* d_out, int out_size, void* d_ws, size_t ws_size,
                              hipStream_t stream)
{
  const float* img=(const float*)d_in[0];
  float* out=(float*)d_out;
  char* wsb=(char*)d_ws;
  float* gray=(float*)wsb;
  float* c1  =(float*)(wsb + (size_t)NPX*4);   // doubles as fr cache before init_cost
  unsigned* meta=(unsigned*)(wsb + (size_t)NPX*8);
  float* c2 = out;   // c2 initial state lives in d_out (fully rewritten each launch)

  unsigned* hist1=meta;            // 2048
  unsigned* hist2=meta+2048;       // 4*2048
  unsigned* hist3=meta+10240;      // 4*1024
  unsigned* sel1 =meta+14336;
  unsigned* rem1 =meta+14340;
  unsigned* sel2 =meta+14344;
  unsigned* rem2 =meta+14348;
  float*    scal =(float*)(meta+14352);   // 2
  int*      flagIt=(int*)(meta+14354);    // 1  -> total 14355 u32

  hipMemsetAsync(meta, 0, 14355*sizeof(unsigned), stream);
  hipLaunchKernelGGL(gray_kernel, dim3(4096), dim3(256), 0, stream, img, gray);
  hipLaunchKernelGGL(sobel_hist1, dim3(1024), dim3(256), 0, stream, gray, c1, hist1);
  hipLaunchKernelGGL(scan_l1, dim3(1), dim3(1024), 0, stream, hist1, sel1, rem1);
  hipLaunchKernelGGL(hist_l2, dim3(1024), dim3(256), 0, stream, c1, sel1, hist2);
  hipLaunchKernelGGL(scan_l2, dim3(1), dim3(1024), 0, stream, hist2, rem1, sel2, rem2);
  hipLaunchKernelGGL(hist_l3, dim3(1024), dim3(256), 0, stream, c1, sel1, sel2, hist3);
  hipLaunchKernelGGL(scan_l3, dim3(1), dim3(1024), 0, stream, hist3, sel1, sel2, rem2, scal);
  hipLaunchKernelGGL(init_cost, dim3(4096), dim3(256), 0, stream, gray, c1, scal, c1, c2);

  void* args[]={ (void*)&c1,(void*)&gray,(void*)&out,(void*)&flagIt };
  (void)hipLaunchCooperativeKernel(ws_solve, dim3(NTL), dim3(1024), args, 0, stream);
}

// Round 7
// 599.254 us; speedup vs baseline: 2.4777x; 1.9012x over previous
//
#include <hip/hip_runtime.h>
#include <hip/hip_cooperative_groups.h>

#define HH 2048
#define WW 2048
#define NPX (HH*WW)
#define INFV 1e30f
#define TS 128        /* tile size for persistent solver */
#define NT 16         /* tiles per dimension */
#define NTL 256       /* total tiles = blocks */
#define CY 32         /* relax cycles per grid-sync window */

namespace cg = cooperative_groups;

// raw barrier: LDS-drain only; outstanding global (halo poll) loads stay in flight
__device__ __forceinline__ void BARL(){
  __builtin_amdgcn_sched_barrier(0);
  asm volatile("s_waitcnt lgkmcnt(0)" ::: "memory");
  __builtin_amdgcn_s_barrier();
  __builtin_amdgcn_sched_barrier(0);
}

// ---------- shared math (pinned rounding so every pass computes identical fr) ----------
__device__ __forceinline__ float sobel_at(const float* __restrict__ g, int y, int x){
  float a00,a01,a02,a10,a12,a20,a21,a22;
  if (y>0 && y<HH-1 && x>0 && x<WW-1){
    const float* p = g + (size_t)(y-1)*WW + x;
    a00=p[-1]; a01=p[0]; a02=p[1];
    p += WW;   a10=p[-1];          a12=p[1];
    p += WW;   a20=p[-1]; a21=p[0]; a22=p[1];
  } else {
    auto at=[&](int yy,int xx)->float{
      return (yy<0||yy>=HH||xx<0||xx>=WW)?0.0f:g[(size_t)yy*WW+xx];
    };
    a00=at(y-1,x-1); a01=at(y-1,x); a02=at(y-1,x+1);
    a10=at(y,  x-1);                a12=at(y,  x+1);
    a20=at(y+1,x-1); a21=at(y+1,x); a22=at(y+1,x+1);
  }
  float gx = __fadd_rn(__fadd_rn(__fsub_rn(a02,a00), __fmul_rn(2.0f,__fsub_rn(a12,a10))), __fsub_rn(a22,a20));
  float gy = __fadd_rn(__fadd_rn(__fsub_rn(a20,a00), __fmul_rn(2.0f,__fsub_rn(a21,a01))), __fsub_rn(a22,a02));
  return sqrtf(__fadd_rn(__fmul_rn(gx,gx),__fmul_rn(gy,gy)));
}

// ---------- gray ----------
__global__ void gray_kernel(const float* __restrict__ img, float* __restrict__ gray){
  const float* R=img; const float* G=img+NPX; const float* B=img+2*(size_t)NPX;
  for (int i=blockIdx.x*blockDim.x+threadIdx.x; i<NPX; i+=gridDim.x*blockDim.x){
    gray[i] = __fadd_rn(__fadd_rn(__fmul_rn(0.2989f,R[i]),__fmul_rn(0.587f,G[i])),__fmul_rn(0.114f,B[i]));
  }
}

// ---------- sobel once, cached to fr; level-1 histogram fused ----------
__global__ void sobel_hist1(const float* __restrict__ gray, float* __restrict__ fr,
                            unsigned* __restrict__ hist){
  __shared__ unsigned h[4*2048];
  for (int i=threadIdx.x;i<4*2048;i+=blockDim.x) h[i]=0;
  __syncthreads();
  const int rep=(threadIdx.x&3)*2048;
  for (int i=blockIdx.x*blockDim.x+threadIdx.x; i<NPX; i+=gridDim.x*blockDim.x){
    int y=i>>11, x=i&(WW-1);
    float f=sobel_at(gray,y,x);
    fr[i]=f;
    unsigned key=__float_as_uint(f);
    atomicAdd(&h[rep+(key>>21)],1u);
  }
  __syncthreads();
  for (int i=threadIdx.x;i<2048;i+=blockDim.x){
    unsigned s=h[i]+h[i+2048]+h[i+4096]+h[i+6144];
    if (s) atomicAdd(&hist[i],s);
  }
}

__global__ void hist_l2(const float* __restrict__ fr, const unsigned* __restrict__ sel1,
                        unsigned* __restrict__ hist2){
  __shared__ unsigned h[4*2048];
  __shared__ unsigned sb[4];
  if (threadIdx.x<4) sb[threadIdx.x]=sel1[threadIdx.x];
  for (int i=threadIdx.x;i<4*2048;i+=blockDim.x) h[i]=0;
  __syncthreads();
  for (int i=blockIdx.x*blockDim.x+threadIdx.x; i<NPX; i+=gridDim.x*blockDim.x){
    unsigned key=__float_as_uint(fr[i]);
    unsigned b=key>>21, sub=(key>>10)&0x7FFu;
    #pragma unroll
    for (int k=0;k<4;++k) if (b==sb[k]) atomicAdd(&h[k*2048+sub],1u);
  }
  __syncthreads();
  for (int i=threadIdx.x;i<4*2048;i+=blockDim.x){ unsigned s=h[i]; if (s) atomicAdd(&hist2[i],s); }
}

__global__ void hist_l3(const float* __restrict__ fr, const unsigned* __restrict__ sel1,
                        const unsigned* __restrict__ sel2, unsigned* __restrict__ hist3){
  __shared__ unsigned h[4*1024];
  __shared__ unsigned pf[4];
  if (threadIdx.x<4) pf[threadIdx.x]=(sel1[threadIdx.x]<<11)|sel2[threadIdx.x];
  for (int i=threadIdx.x;i<4*1024;i+=blockDim.x) h[i]=0;
  __syncthreads();
  for (int i=blockIdx.x*blockDim.x+threadIdx.x; i<NPX; i+=gridDim.x*blockDim.x){
    unsigned key=__float_as_uint(fr[i]);
    unsigned p22=key>>10, sub=key&0x3FFu;
    #pragma unroll
    for (int k=0;k<4;++k) if (p22==pf[k]) atomicAdd(&h[k*1024+sub],1u);
  }
  __syncthreads();
  for (int i=threadIdx.x;i<4*1024;i+=blockDim.x){ unsigned s=h[i]; if (s) atomicAdd(&hist3[i],s); }
}

// ranks: floor(0.9825*(n-1))=4120902, floor(0.9925*(n-1))=4162845 (and +1 each)
__global__ void scan_l1(const unsigned* __restrict__ hist, unsigned* __restrict__ sel1,
                        unsigned* __restrict__ rem1){
  __shared__ unsigned part[1024];
  const int t=threadIdx.x;
  unsigned a=hist[2*t], b=hist[2*t+1];
  part[t]=a+b; __syncthreads();
  for (int off=1;off<1024;off<<=1){
    unsigned add=(t>=off)?part[t-off]:0u; __syncthreads();
    part[t]+=add; __syncthreads();
  }
  unsigned before=(t>0)?part[t-1]:0u;
  const unsigned R[4]={4120902u,4120903u,4162845u,4162846u};
  unsigned cum=before;
  #pragma unroll
  for (int i=0;i<4;++i) if (R[i]>=cum && R[i]<cum+a){ sel1[i]=2*t;   rem1[i]=R[i]-cum; }
  cum+=a;
  #pragma unroll
  for (int i=0;i<4;++i) if (R[i]>=cum && R[i]<cum+b){ sel1[i]=2*t+1; rem1[i]=R[i]-cum; }
}

__global__ void scan_l2(const unsigned* __restrict__ hist2, const unsigned* __restrict__ rem1,
                        unsigned* __restrict__ sel2, unsigned* __restrict__ rem2){
  __shared__ unsigned part[1024];
  const int t=threadIdx.x;
  for (int i=0;i<4;++i){
    const unsigned* hh=hist2+i*2048;
    unsigned a=hh[2*t], b=hh[2*t+1];
    part[t]=a+b; __syncthreads();
    for (int off=1;off<1024;off<<=1){
      unsigned add=(t>=off)?part[t-off]:0u; __syncthreads();
      part[t]+=add; __syncthreads();
    }
    unsigned before=(t>0)?part[t-1]:0u;
    unsigned r=rem1[i], cum=before;
    if (r>=cum && r<cum+a){ sel2[i]=2*t;   rem2[i]=r-cum; }
    cum+=a;
    if (r>=cum && r<cum+b){ sel2[i]=2*t+1; rem2[i]=r-cum; }
    __syncthreads();
  }
}

__global__ void scan_l3(const unsigned* __restrict__ hist3, const unsigned* __restrict__ sel1,
                        const unsigned* __restrict__ sel2, const unsigned* __restrict__ rem2,
                        float* __restrict__ scal){
  __shared__ unsigned part[1024];
  __shared__ float vals[4];
  const int t=threadIdx.x;
  for (int i=0;i<4;++i){
    unsigned c=hist3[i*1024+t];
    part[t]=c; __syncthreads();
    for (int off=1;off<1024;off<<=1){
      unsigned add=(t>=off)?part[t-off]:0u; __syncthreads();
      part[t]+=add; __syncthreads();
    }
    unsigned before=(t>0)?part[t-1]:0u;
    unsigned r=rem2[i];
    if (r>=before && r<before+c){
      unsigned key=(sel1[i]<<21)|(sel2[i]<<10)|(unsigned)t;
      vals[i]=__uint_as_float(key);
    }
    __syncthreads();
  }
  if (t==0){
    scal[0]=__fadd_rn(__fmul_rn(vals[0],0.25f),__fmul_rn(vals[1],0.75f));
    scal[1]=__fadd_rn(__fmul_rn(vals[2],0.25f),__fmul_rn(vals[3],0.75f));
  }
}

// ---------- markers -> initial costs ----------
// Field 1 = c1 (seeds: markers==1).  Field 2 = c := min(c1,c2) = flood from the
// UNION of seeds (markers!=0).  Identity: c2 < c1  <=>  c < c1, and flood from a
// union of seed sets equals the pointwise min of the individual floods (pure
// min/max lattice, exact).  Union seeds are ~99% dense -> both fields converge
// via LOCAL gap-filling instead of c2's long-range percolation settling.
__global__ void init_cost(const float* __restrict__ gray, const float* frbuf,
                          const float* __restrict__ scal,
                          float* c1out, float* __restrict__ c2out){
  const float qlo=scal[0], qhi=scal[1];
  for (int i=blockIdx.x*blockDim.x+threadIdx.x; i<NPX; i+=gridDim.x*blockDim.x){
    float f=frbuf[i];
    float g=gray[i];
    bool m1 = (f<=qlo);
    bool m2 = (!m1) && (f>=qhi);
    c1out[i] = m1 ? g : INFV;
    c2out[i] = (m1|m2) ? g : INFV;   // union-seed combined field
  }
}

// ---------- persistent-tile cooperative fixed-point solver ----------
// clamp composition: f_cur(f_prev(v)) with f=(lo,hi)->min(hi,max(lo,v)):
//   hi' = min(hi_cur, max(lo_cur, hi_prev)); lo' = max(lo_cur, lo_prev)

#define HSCAN_LR(va,vb,gA,gB,hl) do{ \
  float ql_=gA[j], qh_=va[j]; \
  qh_=fminf(vb[j],fmaxf(gB[j],qh_)); ql_=fmaxf(gB[j],ql_); \
  _Pragma("unroll") \
  for (int d_=1;d_<64;d_<<=1){ \
    float pl_=__shfl_up(ql_,(unsigned)d_), ph_=__shfl_up(qh_,(unsigned)d_); \
    if (c>=d_){ qh_=fminf(qh_,fmaxf(ql_,ph_)); ql_=fmaxf(ql_,pl_); } \
  } \
  float E_=fminf(qh_,fmaxf(ql_,(hl))); \
  float In_=__shfl_up(E_,1u); if(c==0) In_=(hl); \
  float na_=fminf(va[j],fmaxf(gA[j],In_)); if(na_<va[j]){va[j]=na_;ch=true;} \
  float nb_=fminf(vb[j],fmaxf(gB[j],na_)); if(nb_<vb[j]){vb[j]=nb_;ch=true;} \
}while(0)

#define HSCAN_RL(va,vb,gA,gB,hr) do{ \
  float ql_=gB[j], qh_=vb[j]; \
  qh_=fminf(va[j],fmaxf(gA[j],qh_)); ql_=fmaxf(gA[j],ql_); \
  _Pragma("unroll") \
  for (int d_=1;d_<64;d_<<=1){ \
    float pl_=__shfl_down(ql_,(unsigned)d_), ph_=__shfl_down(qh_,(unsigned)d_); \
    if (c+d_<64){ qh_=fminf(qh_,fmaxf(ql_,ph_)); ql_=fmaxf(ql_,pl_); } \
  } \
  float E_=fminf(qh_,fmaxf(ql_,(hr))); \
  float In_=__shfl_down(E_,1u); if(c==63) In_=(hr); \
  float nb_=fminf(vb[j],fmaxf(gB[j],In_)); if(nb_<vb[j]){vb[j]=nb_;ch=true;} \
  float na_=fminf(va[j],fmaxf(gA[j],nb_)); if(na_<va[j]){va[j]=na_;ch=true;} \
}while(0)

#define VCOMP_DN(va,gA,Larr,Harr,XX) { float ql_=gA[0], qh_=va[0]; \
  _Pragma("unroll") for (int jj_=1;jj_<8;++jj_){ qh_=fminf(va[jj_],fmaxf(gA[jj_],qh_)); ql_=fmaxf(gA[jj_],ql_);} \
  Larr[w][XX]=ql_; Harr[w][XX]=qh_; }

#define VCOMP_UP(va,gA,Larr,Harr,XX) { float ql_=gA[7], qh_=va[7]; \
  _Pragma("unroll") for (int jj_=6;jj_>=0;--jj_){ qh_=fminf(va[jj_],fmaxf(gA[jj_],qh_)); ql_=fmaxf(gA[jj_],ql_);} \
  Larr[w][XX]=ql_; Harr[w][XX]=qh_; }

#define VAPPLY_DN(va,gA,Larr,XX) { float In_=Larr[w][XX]; \
  _Pragma("unroll") for (int jj_=0;jj_<8;++jj_){ float nv_=fminf(va[jj_],fmaxf(In_,gA[jj_])); if(nv_<va[jj_]){va[jj_]=nv_;ch=true;} In_=nv_; } }

#define VAPPLY_UP(va,gA,Larr,XX) { float In_=Larr[w][XX]; \
  _Pragma("unroll") for (int jj_=7;jj_>=0;--jj_){ float nv_=fminf(va[jj_],fmaxf(In_,gA[jj_])); if(nv_<va[jj_]){va[jj_]=nv_;ch=true;} In_=nv_; } }

#define CHAIN_DN(Harr,Larr,HT) { float E=HALO[HT][x]; \
  _Pragma("unroll") for (int b_=0;b_<16;++b_){ float I=E; E=fminf(Harr[b_][x],fmaxf(Larr[b_][x],I)); Larr[b_][x]=I; } }

#define CHAIN_UP(Harr,Larr,HB) { float E=HALO[HB][x]; \
  _Pragma("unroll") for (int b_=15;b_>=0;--b_){ float I=E; E=fminf(Harr[b_][x],fmaxf(Larr[b_][x],I)); Larr[b_][x]=I; } }

#define HFIELD(va,vb,IHL,IHR) do{ \
  _Pragma("unroll") \
  for (int j=0;j<8;++j){ \
    const int r_=(w<<3)|j; \
    const float hl=HALO[IHL][r_], hr=HALO[IHR][r_]; \
    { float la_=__shfl_up(vb[j],1u); if(c==0) la_=hl; \
      bool p_=__any((fminf(va[j],fmaxf(la_,ga[j]))<va[j])||(fminf(vb[j],fmaxf(va[j],gb[j]))<vb[j])); \
      if (p_){ HSCAN_LR(va,vb,ga,gb,hl); } } \
    { float ra_=__shfl_down(va[j],1u); if(c==63) ra_=hr; \
      bool p_=__any((fminf(vb[j],fmaxf(ra_,gb[j]))<vb[j])||(fminf(va[j],fmaxf(vb[j],ga[j]))<va[j])); \
      if (p_){ HSCAN_RL(va,vb,ga,gb,hr); } } \
  } \
}while(0)

#define ASTORE(p,v) __hip_atomic_store((p),(v),__ATOMIC_RELAXED,__HIP_MEMORY_SCOPE_AGENT)
#define ALOAD(p)    __hip_atomic_load((p),__ATOMIC_RELAXED,__HIP_MEMORY_SCOPE_AGENT)

__global__ void __launch_bounds__(1024,4)
ws_solve(float* __restrict__ c1g, const float* __restrict__ grayg, float* outg,
         int* __restrict__ flagIt)
{
  __shared__ float DNL1[16][128], DNH1[16][128], DNL2[16][128], DNH2[16][128];
  __shared__ float UPL1[16][128], UPH1[16][128], UPL2[16][128], UPH2[16][128];
  __shared__ float HALO[8][128];   // 0 Ht1,1 Ht2,2 Hb1,3 Hb2,4 Hl1,5 Hl2,6 Hr1,7 Hr2
  __shared__ int F1[3], F2[3];
  __shared__ int wflag;
  cg::grid_group grid = cg::this_grid();
  const int tid=threadIdx.x, w=tid>>6, c=tid&63;
  // XCD-chunked tile mapping: each of 8 XCDs (blockIdx%8, assuming round-robin)
  // owns a 4x8-tile region so most neighbor edges are same-L2. Perf heuristic only.
  const int xcd=blockIdx.x&7, idx=blockIdx.x>>3;
  const int tx=((xcd&3)<<2)|(idx&3), ty=((xcd>>2)<<3)|(idx>>2);
  const int tile=ty*NT+tx;
  const int by=ty*TS, bx=tx*TS, x0=c<<1;
  float* EB1=outg;
  float* EB2=outg+(NTL*4*128);

  // this thread's halo poll slot (1024 threads <-> 8 arrays x 128 entries)
  const int hx=tid&127, harr=tid>>7;
  const float* hsrc=nullptr;
  {
    const float* EB=(harr&1)?EB2:EB1;
    switch(harr>>1){
      case 0: if (ty>0)    hsrc=EB+((tile-NT)*4+1)*128+hx; break;
      case 1: if (ty<NT-1) hsrc=EB+((tile+NT)*4+0)*128+hx; break;
      case 2: if (tx>0)    hsrc=EB+((tile-1)*4+3)*128+hx;  break;
      default:if (tx<NT-1) hsrc=EB+((tile+1)*4+2)*128+hx;  break;
    }
  }

  float v1a[8],v1b[8],v2a[8],v2b[8],ga[8],gb[8];
  {
    size_t base=(size_t)(by+(w<<3))*WW + bx + x0;
    #pragma unroll
    for (int j=0;j<8;++j){
      float2 t1=*(const float2*)(c1g+base);
      float2 t2=*(const float2*)(outg+base);   // field-2 initial lives in d_out
      float2 tg=*(const float2*)(grayg+base);
      v1a[j]=t1.x; v1b[j]=t1.y; v2a[j]=t2.x; v2b[j]=t2.y; ga[j]=tg.x; gb[j]=tg.y;
      base+=(size_t)WW;
    }
  }
  grid.sync();   // all field-2 loads complete before edge buffers overwrite d_out

  // pre-publish initial edges so halos are live from the first cycle
  if (w==0){ const int eb=(tile*4+0)*128;
    ASTORE(EB1+eb+x0,v1a[0]); ASTORE(EB1+eb+x0+1,v1b[0]);
    ASTORE(EB2+eb+x0,v2a[0]); ASTORE(EB2+eb+x0+1,v2b[0]); }
  if (w==15){ const int eb=(tile*4+1)*128;
    ASTORE(EB1+eb+x0,v1a[7]); ASTORE(EB1+eb+x0+1,v1b[7]);
    ASTORE(EB2+eb+x0,v2a[7]); ASTORE(EB2+eb+x0+1,v2b[7]); }
  if (c==0){ const int eb=(tile*4+2)*128+(w<<3);
    #pragma unroll
    for (int j=0;j<8;++j){ ASTORE(EB1+eb+j,v1a[j]); ASTORE(EB2+eb+j,v2a[j]); } }
  if (c==63){ const int eb=(tile*4+3)*128+(w<<3);
    #pragma unroll
    for (int j=0;j<8;++j){ ASTORE(EB1+eb+j,v1b[j]); ASTORE(EB2+eb+j,v2b[j]); } }
  HALO[harr][hx]=INFV;
  if (tid==0){ F1[0]=1;F2[0]=1;F1[1]=0;F2[1]=0;F1[2]=0;F2[2]=0; wflag=0; }
  float hv=0.0f; bool hvok=false;
  __threadfence();
  grid.sync();

  for (int win=0; win<192; ++win){
    for (int cyc=0; cyc<CY; ++cyc){
      const int gc=win*CY+cyc;
      const int cur=gc%3, nxt=(gc+1)%3, old=(gc+2)%3;
      // consume previous poll, reissue (every cycle; load floats across raw barriers)
      if (hsrc){
        if (hvok && hv<HALO[harr][hx]){
          HALO[harr][hx]=hv;
          if (harr&1) F2[nxt]=1; else F1[nxt]=1;
        }
        hv=ALOAD(hsrc); hvok=true;
      }
      const int r1=F1[cur], r2=F2[cur];
      if (tid==0){ F1[old]=0; F2[old]=0; }
      if (!(r1|r2)){ BARL(); continue; }
      // ---- P1: band compose, both directions, dirty fields ----
      if (r1){
        VCOMP_DN(v1a,ga,DNL1,DNH1,x0) VCOMP_DN(v1b,gb,DNL1,DNH1,x0+1)
        VCOMP_UP(v1a,ga,UPL1,UPH1,x0) VCOMP_UP(v1b,gb,UPL1,UPH1,x0+1)
      }
      if (r2){
        VCOMP_DN(v2a,ga,DNL2,DNH2,x0) VCOMP_DN(v2b,gb,DNL2,DNH2,x0+1)
        VCOMP_UP(v2a,ga,UPL2,UPH2,x0) VCOMP_UP(v2b,gb,UPL2,UPH2,x0+1)
      }
      BARL();
      // ---- P2: cross-band chains (8 waves, 1 col/lane) ----
      if (w<8){
        const int x=((w&1)<<6)|c;
        const bool go = (w>>2) ? (r2!=0) : (r1!=0);
        if (go){
          switch(w>>1){
            case 0: CHAIN_DN(DNH1,DNL1,0) break;
            case 1: CHAIN_UP(UPH1,UPL1,2) break;
            case 2: CHAIN_DN(DNH2,DNL2,1) break;
            default:CHAIN_UP(UPH2,UPL2,3) break;
          }
        }
      }
      BARL();
      // ---- P3: vertical apply + horizontal scans + flags + publish ----
      bool chf1=false, chf2=false;
      if (r1){ bool ch=false;
        VAPPLY_DN(v1a,ga,DNL1,x0) VAPPLY_DN(v1b,gb,DNL1,x0+1)
        VAPPLY_UP(v1a,ga,UPL1,x0) VAPPLY_UP(v1b,gb,UPL1,x0+1)
        HFIELD(v1a,v1b,4,6);
        if (ch){ F1[nxt]=1; wflag=1; chf1=true; }
      }
      if (r2){ bool ch=false;
        VAPPLY_DN(v2a,ga,DNL2,x0) VAPPLY_DN(v2b,gb,DNL2,x0+1)
        VAPPLY_UP(v2a,ga,UPL2,x0) VAPPLY_UP(v2b,gb,UPL2,x0+1)
        HFIELD(v2a,v2b,5,7);
        if (ch){ F2[nxt]=1; wflag=1; chf2=true; }
      }
      if (chf1|chf2){
        if (w==0){ const int eb=(tile*4+0)*128;
          if(chf1){ ASTORE(EB1+eb+x0,v1a[0]); ASTORE(EB1+eb+x0+1,v1b[0]); }
          if(chf2){ ASTORE(EB2+eb+x0,v2a[0]); ASTORE(EB2+eb+x0+1,v2b[0]); } }
        if (w==15){ const int eb=(tile*4+1)*128;
          if(chf1){ ASTORE(EB1+eb+x0,v1a[7]); ASTORE(EB1+eb+x0+1,v1b[7]); }
          if(chf2){ ASTORE(EB2+eb+x0,v2a[7]); ASTORE(EB2+eb+x0+1,v2b[7]); } }
        if (c==0){ const int eb=(tile*4+2)*128+(w<<3);
          #pragma unroll
          for (int j=0;j<8;++j){ if(chf1)ASTORE(EB1+eb+j,v1a[j]); if(chf2)ASTORE(EB2+eb+j,v2a[j]); } }
        if (c==63){ const int eb=(tile*4+3)*128+(w<<3);
          #pragma unroll
          for (int j=0;j<8;++j){ if(chf1)ASTORE(EB1+eb+j,v1b[j]); if(chf2)ASTORE(EB2+eb+j,v2b[j]); } }
      }
      BARL();
    }
    // window end: termination handshake
    if (tid==0 && wflag) atomicMax(flagIt,win+1);
    __threadfence();
    grid.sync();
    int fv=ALOAD(flagIt);
    if (fv<=win) break;   // a full window with zero changes anywhere -> fixed point
    if (tid==0) wflag=0;
    __syncthreads();
  }
  // fused label output: out = (c < c1) ? 1 : 0   (== (c2 < c1))
  {
    size_t base=(size_t)(by+(w<<3))*WW + bx + x0;
    #pragma unroll
    for (int j=0;j<8;++j){
      float2 o; o.x=(v2a[j]<v1a[j])?1.0f:0.0f; o.y=(v2b[j]<v1b[j])?1.0f:0.0f;
      *(float2*)(outg+base)=o;
      base+=(size_t)WW;
    }
  }
}

extern "C" void kernel_launch(void* const* d_in, const int* in_sizes, int n_in,
                              void* d_out, int out_size, void* d_ws, size_t ws_size,
                              hipStream_t stream)
{
  const float* img=(const float*)d_in[0];
  float* out=(float*)d_out;
  char* wsb=(char*)d_ws;
  float* gray=(float*)wsb;
  float* c1  =(float*)(wsb + (size_t)NPX*4);   // doubles as fr cache before init_cost
  unsigned* meta=(unsigned*)(wsb + (size_t)NPX*8);
  float* c2 = out;   // field-2 initial state lives in d_out (fully rewritten each launch)

  unsigned* hist1=meta;            // 2048
  unsigned* hist2=meta+2048;       // 4*2048
  unsigned* hist3=meta+10240;      // 4*1024
  unsigned* sel1 =meta+14336;
  unsigned* rem1 =meta+14340;
  unsigned* sel2 =meta+14344;
  unsigned* rem2 =meta+14348;
  float*    scal =(float*)(meta+14352);   // 2
  int*      flagIt=(int*)(meta+14354);    // 1  -> total 14355 u32

  hipMemsetAsync(meta, 0, 14355*sizeof(unsigned), stream);
  hipLaunchKernelGGL(gray_kernel, dim3(4096), dim3(256), 0, stream, img, gray);
  hipLaunchKernelGGL(sobel_hist1, dim3(1024), dim3(256), 0, stream, gray, c1, hist1);
  hipLaunchKernelGGL(scan_l1, dim3(1), dim3(1024), 0, stream, hist1, sel1, rem1);
  hipLaunchKernelGGL(hist_l2, dim3(1024), dim3(256), 0, stream, c1, sel1, hist2);
  hipLaunchKernelGGL(scan_l2, dim3(1), dim3(1024), 0, stream, hist2, rem1, sel2, rem2);
  hipLaunchKernelGGL(hist_l3, dim3(1024), dim3(256), 0, stream, c1, sel1, sel2, hist3);
  hipLaunchKernelGGL(scan_l3, dim3(1), dim3(1024), 0, stream, hist3, sel1, sel2, rem2, scal);
  hipLaunchKernelGGL(init_cost, dim3(4096), dim3(256), 0, stream, gray, c1, scal, c1, c2);

  void* args[]={ (void*)&c1,(void*)&gray,(void*)&out,(void*)&flagIt };
  (void)hipLaunchCooperativeKernel(ws_solve, dim3(NTL), dim3(1024), args, 0, stream);
}